// Round 4
// baseline (428.397 us; speedup 1.0000x reference)
//
#include <hip/hip_runtime.h>

typedef unsigned short u16;
typedef unsigned int u32;
typedef __bf16 bf16_t;
typedef bf16_t bf16x8 __attribute__((ext_vector_type(8)));
typedef float f32x16 __attribute__((ext_vector_type(16)));

#define DIM 2048
#define HW  192
#define CP  256
#define NB  80

__device__ __forceinline__ u16 f2b(float f) {
    u32 u = __float_as_uint(f);
    u32 r = (u + 0x7FFFu + ((u >> 16) & 1u)) >> 16;   // RNE
    return (u16)r;
}

__device__ __forceinline__ void g2l16(const void* g, void* l) {
    __builtin_amdgcn_global_load_lds(
        (const __attribute__((address_space(1))) u32*)g,
        (__attribute__((address_space(3))) u32*)l, 16, 0, 0);
}

// T1 XCD swizzle: cluster consecutive (act-panel-sharing) block ids on one XCD.
// n must be divisible by 8; bijective chunked remap [m204].
__device__ __forceinline__ int xcdswz(int lid, int n) {
    return (lid & 7) * (n >> 3) + (lid >> 3);
}

// ---------------------------------------------------------------------------
// MFMA GEMM core v4. Block = 256 threads (4 waves). Output tile 192(n)x128(m);
// wave grid 2x2: wave w -> rows (w>>1)*96, cols (w&1)*64. Per wave: 3x2 MFMA
// tiles of 32x32 (mfma_f32_32x32x16_bf16), acc = 96 VGPRs/lane.
// Double-buffered LDS 41 KB: stage k+1 overlaps MFMA k.
// act: [192][K] bf16 k-major (row ptr via functor, stride arstride).
// W: [128][K] bf16 row stride wstride. XOR-chunk swizzle (chunk ^= (row>>1)&3)
// breaks bank aliasing of the 64B rows forced by global_load_lds.
// A/B frag: row = lane&31, k = (lane>>5)*8 + e. D: col = lane&31,
// row = (r&3) + 8*(r>>2) + 4*(lane>>5)  [m74/m101].
// ---------------------------------------------------------------------------
template<int ACT, bool OUTF32, typename F>   // ACT 0=none 1=relu
__device__ __forceinline__ void gemm_core(F actAddr, int arstride,
    const u16* __restrict__ Wp, int wstride, int K,
    void* __restrict__ outp, int M)
{
    __shared__ u16 act_s[2][192 * 32];
    __shared__ u16 w_s[2][128 * 32];
    const int t    = threadIdx.x;      // 0..255
    const int wv   = t >> 6;           // wave id
    const int wn   = wv >> 1;          // n-half: rows wn*96
    const int wm   = wv & 1;           // m-half: cols wm*64
    const int lane = t & 63;
    const int ln   = lane & 31;
    const int q2   = lane >> 5;        // 0/1
    const int swz  = (ln >> 1) & 3;

    f32x16 acc[3][2];
    #pragma unroll
    for (int i = 0; i < 3; ++i)
        #pragma unroll
        for (int j = 0; j < 2; ++j)
            #pragma unroll
            for (int r = 0; r < 16; ++r) acc[i][j][r] = 0.f;

    auto stage = [&](int buf, int k0) {
        const u16* ap = actAddr(k0);
        #pragma unroll
        for (int r = 0; r < 2; ++r) {            // W: 512 16B slots / 256 thr
            int idx = r * 256 + t;
            int row = idx >> 2, pc = idx & 3;
            int lc  = pc ^ ((row >> 1) & 3);
            g2l16(Wp + (size_t)row * wstride + k0 + lc * 8, (void*)(w_s[buf] + idx * 8));
        }
        #pragma unroll
        for (int r = 0; r < 3; ++r) {            // act: 768 16B slots / 256 thr
            int idx = r * 256 + t;
            int row = idx >> 2, pc = idx & 3;
            int lc  = pc ^ ((row >> 1) & 3);
            g2l16(ap + (size_t)row * arstride + lc * 8, (void*)(act_s[buf] + idx * 8));
        }
    };

    auto compute = [&](int buf) {
        #pragma unroll
        for (int s = 0; s < 2; ++s) {            // two 16-k steps per 32-k tile
            bf16x8 af[3], bf[2];
            const int phys = (s * 2 + q2) ^ swz;
            #pragma unroll
            for (int i = 0; i < 3; ++i)
                af[i] = *(const bf16x8*)(act_s[buf] + ((wn * 96 + i * 32 + ln) * 32 + phys * 8));
            #pragma unroll
            for (int j = 0; j < 2; ++j)
                bf[j] = *(const bf16x8*)(w_s[buf] + ((wm * 64 + j * 32 + ln) * 32 + phys * 8));
            #pragma unroll
            for (int i = 0; i < 3; ++i)
                #pragma unroll
                for (int j = 0; j < 2; ++j)
                    acc[i][j] = __builtin_amdgcn_mfma_f32_32x32x16_bf16(
                        af[i], bf[j], acc[i][j], 0, 0, 0);
        }
    };

    stage(0, 0);
    const int iters = K / 32;
    for (int it = 0; it < iters; ++it) {
        int b = it & 1;
        __syncthreads();                // waits prev stage's g2l + frag reads
        if (it + 1 < iters) stage(b ^ 1, (it + 1) * 32);
        compute(b);
    }

    #pragma unroll
    for (int i = 0; i < 3; ++i) {
        #pragma unroll
        for (int j = 0; j < 2; ++j) {
            #pragma unroll
            for (int r = 0; r < 16; ++r) {
                float v = acc[i][j][r];
                if (ACT == 1) v = v > 0.f ? v : 0.f;
                int nl = wn * 96 + i * 32 + (r & 3) + 8 * (r >> 2) + 4 * q2;
                int ml = wm * 64 + j * 32 + ln;
                if (OUTF32) ((float*)outp)[(size_t)nl * M + ml] = v;
                else        ((u16*)outp)[(size_t)nl * M + ml] = f2b(v);
            }
        }
    }
}

// proj, K-split x4: proj4[p][n][pix][o] = sum_{c in p*512..+512} x[n][c][pix]*Wr[o][c]
// fp32 partials. 640 blocks x 4 waves = 2.5 blocks/CU. XCD-swizzled.
__global__ __launch_bounds__(256) void proj_g(const u16* __restrict__ xt,
    const int* __restrict__ sub, int nbase,
    const u16* __restrict__ Wri, const u16* __restrict__ Wrv,
    float* __restrict__ proj4)
{
    const int nblk = gridDim.x * gridDim.z;
    const int lid  = blockIdx.x + gridDim.x * blockIdx.z;
    const int s    = xcdswz(lid, nblk);
    const int bm = s & 1, zz = s >> 1;
    const int z = zz >> 2, p = zz & 3;
    const int n = nbase + z;
    const u16* act = xt + (size_t)z * (HW * DIM) + p * 512;
    const u16* Wp  = ((sub[n] != 0) ? Wri : Wrv) + (size_t)bm * 128 * DIM + p * 512;
    float* outp = proj4 + (size_t)p * ((size_t)NB * HW * CP)
                + (size_t)n * (HW * CP) + bm * 128;
    auto f = [=](int k0) { return act + k0; };
    gemm_core<0, true>(f, DIM, Wp, DIM, 512, outp, CP);
}

// sum 4 K-slice partials -> bf16 projt
__global__ __launch_bounds__(256) void proj_red(const float* __restrict__ proj4,
                                                u16* __restrict__ projt)
{
    const size_t i = ((size_t)blockIdx.x * 256 + threadIdx.x) * 4;
    const size_t S = (size_t)NB * HW * CP;
    float4 a = *(const float4*)(proj4 + i);
    float4 b = *(const float4*)(proj4 + i + S);
    float4 c = *(const float4*)(proj4 + i + 2 * S);
    float4 d = *(const float4*)(proj4 + i + 3 * S);
    ushort4 o;
    o.x = f2b(a.x + b.x + c.x + d.x);
    o.y = f2b(a.y + b.y + c.y + d.y);
    o.z = f2b(a.z + b.z + c.z + d.z);
    o.w = f2b(a.w + b.w + c.w + d.w);
    *(ushort4*)(projt + i) = o;
}

// compose: st[id][br][p][o] = relu( sum_kk projt[samp][p][o2] * Wc[o][kk] )
// 256 blocks, XCD-swizzled (16 consecutive lids share one act panel).
__global__ __launch_bounds__(256) void compose_g(const u16* __restrict__ projt,
    const u16* __restrict__ Wci, const u16* __restrict__ Wcv,
    u16* __restrict__ st)
{
    const int lid = blockIdx.x + 16 * blockIdx.z;      // 0..255
    const int s   = xcdswz(lid, 256);
    const int bm = s & 15, z = s >> 4;
    const int br = z >> 3, id = z & 7;
    const u16* base = projt + (size_t)(id * 10 + br * 5) * (HW * CP);
    const u16* Wp   = (br ? Wcv : Wci) + (size_t)bm * 128 * 1280;
    u16* outp = st + (size_t)(id * 2 + br) * (HW * DIM) + bm * 128;
    auto f = [=](int k0) { return base + (size_t)(k0 >> 8) * (HW * CP) + (k0 & 255); };
    gemm_core<1, false>(f, CP, Wp, 1280, 1280, outp, DIM);
}

// fuse, K-split x4 (h=0..3 covers k = h*1024 of [s_i;s_v]); fp32 partials.
// 512 blocks, XCD-swizzled (16 consecutive lids share one act panel).
__global__ __launch_bounds__(256) void fuse_g(const u16* __restrict__ st,
    const u16* __restrict__ Wf, float* __restrict__ fuset4)
{
    const int lid = blockIdx.x + 16 * blockIdx.z;      // 0..511
    const int s   = xcdswz(lid, 512);
    const int bm = s & 15, z = s >> 4;
    const int h = z >> 3, id = z & 7;
    const u16* base = st + (size_t)(id * 2 + (h >> 1)) * (HW * DIM) + (h & 1) * 1024;
    const u16* Wp   = Wf + (size_t)bm * 128 * (2 * DIM) + (size_t)h * 1024;
    float* outp = fuset4 + (size_t)h * (8 * HW * DIM) + (size_t)id * (HW * DIM) + bm * 128;
    auto f = [=](int k0) { return base + k0; };
    gemm_core<0, true>(f, DIM, Wp, 2 * DIM, 1024, outp, DIM);
}

// prep: x transpose-convert + (optionally) weight fp32->bf16, one launch.
// b < nxt: tile [c=64][p=192(all)] of sample z: ONE contiguous 48KB read
// (12 float4/thread), bf16-convert BEFORE LDS (u16 ts[64][210], 26.9KB ->
// 6 blocks/CU), write xt rows as 8x128B full-line uint4 groups.
// b >= nxt: wcvt unit.
__global__ __launch_bounds__(256) void prep_k(const float* __restrict__ x,
    u16* __restrict__ xt, int nxt, int wc,
    const float* __restrict__ a0, const float* __restrict__ a1,
    const float* __restrict__ a2, const float* __restrict__ a3,
    const float* __restrict__ a4,
    u16* __restrict__ o0, u16* __restrict__ o1, u16* __restrict__ o2,
    u16* __restrict__ o3, u16* __restrict__ o4)
{
    __shared__ u16 ts[64][210];   // pad 210: 8-row groups spread 4 bank classes
    const int b = blockIdx.x;
    const int t = threadIdx.x;
    if (b < nxt) {
        const int z = b >> 5, c0 = (b & 31) * 64;
        const float* src = x + ((size_t)z * DIM + c0) * HW;   // 48KB contiguous
        #pragma unroll
        for (int i = 0; i < 12; ++i) {
            int idx = i * 256 + t;               // 0..3071 float4 slots
            float4 v = *(const float4*)(src + (size_t)idx * 4);
            int c = idx / 48, p4 = (idx % 48) * 4;
            u32 lo = ((u32)f2b(v.y) << 16) | f2b(v.x);
            u32 hi = ((u32)f2b(v.w) << 16) | f2b(v.z);
            *(u32*)&ts[c][p4]     = lo;
            *(u32*)&ts[c][p4 + 2] = hi;
        }
        __syncthreads();
        #pragma unroll
        for (int i = 0; i < 6; ++i) {
            int u = i * 256 + t;                 // 0..1535 units of (p, 8 c)
            int c8 = (u & 7) * 8, p = u >> 3;
            u32 w0 = ((u32)ts[c8 + 1][p] << 16) | ts[c8 + 0][p];
            u32 w1 = ((u32)ts[c8 + 3][p] << 16) | ts[c8 + 2][p];
            u32 w2 = ((u32)ts[c8 + 5][p] << 16) | ts[c8 + 4][p];
            u32 w3 = ((u32)ts[c8 + 7][p] << 16) | ts[c8 + 6][p];
            uint4 o4v; o4v.x = w0; o4v.y = w1; o4v.z = w2; o4v.w = w3;
            *(uint4*)(xt + ((size_t)z * HW + p) * DIM + c0 + c8) = o4v;
        }
    } else if (wc) {
        size_t off = ((size_t)(b - nxt) * 256 + t) * 4;
        const float* s; u16* d;
        if (off < 524288)                    { s = a0; d = o0; }
        else if ((off -= 524288) < 524288)   { s = a1; d = o1; }
        else if ((off -= 524288) < 2621440)  { s = a2; d = o2; }
        else if ((off -= 2621440) < 2621440) { s = a3; d = o3; }
        else                                 { off -= 2621440; s = a4; d = o4; }
        float4 v = *(const float4*)(s + off);
        ushort4 p;
        p.x = f2b(v.x); p.y = f2b(v.y); p.z = f2b(v.z); p.w = f2b(v.w);
        *(ushort4*)(d + off) = p;
    }
}

// sum 4 K-split partials, sigmoid, transpose: fuse[id][c][p]
__global__ __launch_bounds__(256) void fuse_tr(const float* __restrict__ fuset4,
                                               float* __restrict__ fuse)
{
    __shared__ float ts[64][65];
    const int id = blockIdx.z;
    const int c0 = blockIdx.x * 64, p0 = blockIdx.y * 64;
    const int t = threadIdx.x, l = t & 63;
    const size_t hs = (size_t)8 * HW * DIM;
    #pragma unroll
    for (int i = 0; i < 16; ++i) {
        int pl = (t >> 6) * 16 + i;
        size_t a = ((size_t)id * HW + p0 + pl) * DIM + c0 + l;
        float v = fuset4[a] + fuset4[a + hs] + fuset4[a + 2 * hs] + fuset4[a + 3 * hs];
        ts[pl][l] = 1.f / (1.f + __expf(-v));
    }
    __syncthreads();
    #pragma unroll
    for (int i = 0; i < 16; ++i) {
        int cl = (t >> 6) * 16 + i;
        fuse[((size_t)id * DIM + c0 + cl) * HW + p0 + l] = ts[l][cl];
    }
}

// out[n][c][p] = x * (1 + fuse[labels[n]][c][p])
__global__ __launch_bounds__(256) void final_kernel(const float* __restrict__ x,
    const int* __restrict__ labels, const float* __restrict__ fusebuf,
    float* __restrict__ out)
{
    const u32 e = ((u32)blockIdx.x * 256u + threadIdx.x) * 4u;
    const u32 n   = e / ((u32)DIM * HW);
    const u32 rem = e % ((u32)DIM * HW);
    const int id  = labels[n];
    float4 xv = *reinterpret_cast<const float4*>(x + e);
    float4 fv = *reinterpret_cast<const float4*>(fusebuf + (size_t)id * DIM * HW + rem);
    float4 o;
    o.x = xv.x + xv.x * fv.x;
    o.y = xv.y + xv.y * fv.y;
    o.z = xv.z + xv.z * fv.z;
    o.w = xv.w + xv.w * fv.w;
    *reinterpret_cast<float4*>(out + e) = o;
}

extern "C" void kernel_launch(void* const* d_in, const int* in_sizes, int n_in,
                              void* d_out, int out_size, void* d_ws, size_t ws_size,
                              hipStream_t stream) {
    const float* x      = (const float*)d_in[0];
    const int*   labels = (const int*)d_in[1];
    const int*   sub    = (const int*)d_in[2];
    const float* Wri    = (const float*)d_in[3];
    const float* Wrv    = (const float*)d_in[4];
    const float* Wci    = (const float*)d_in[5];
    const float* Wcv    = (const float*)d_in[6];
    const float* Wf     = (const float*)d_in[7];
    float* out = (float*)d_out;
    char* ws = (char*)d_ws;

    const bool full = ws_size >= (size_t)175636480;
    const size_t xtb = full ? (size_t)62914560 : (size_t)15728640;

    u16* Wri_b = (u16*)(ws);
    u16* Wrv_b = (u16*)(ws + 1048576);
    u16* Wci_b = (u16*)(ws + 2097152);
    u16* Wcv_b = (u16*)(ws + 7340032);
    u16* Wf_b  = (u16*)(ws + 12582912);
    u16* xtbuf = (u16*)(ws + 29360128);
    u16* projt = (u16*)(ws + 29360128 + xtb);
    u16* stb   = (u16*)(ws + 29360128 + xtb + 7864320);
    float* fuset4 = (float*)(ws + 29360128 + xtb + 7864320 + 12582912);
    float* fuse   = (float*)(ws + 29360128 + xtb + 7864320 + 12582912 + 50331648);
    // proj4 (4 x 15.7 MB fp32 partials) reuses the fuset4+fuse region —
    // dead until fuse_g/fuse_tr; proj4 dead after proj_red.
    float* proj4 = fuset4;

    const int nchunk = full ? 1 : 4;
    const int cs = NB / nchunk;
    for (int c = 0; c < nchunk; ++c) {
        const int nxt = 32 * cs;
        const int wc = (c == 0) ? 1 : 0;
        prep_k<<<nxt + (wc ? 14336 : 0), 256, 0, stream>>>(
            x + (size_t)c * cs * DIM * HW, xtbuf, nxt, wc,
            Wri, Wrv, Wci, Wcv, Wf, Wri_b, Wrv_b, Wci_b, Wcv_b, Wf_b);
        proj_g<<<dim3(2, 1, cs * 4), 256, 0, stream>>>(xtbuf, sub, c * cs, Wri_b, Wrv_b, proj4);
    }
    proj_red<<<3840, 256, 0, stream>>>(proj4, projt);
    compose_g<<<dim3(16, 1, 16), 256, 0, stream>>>(projt, Wci_b, Wcv_b, stb);
    fuse_g   <<<dim3(16, 1, 32), 256, 0, stream>>>(stb, Wf_b, fuset4);
    fuse_tr  <<<dim3(32, 3, 8), 256, 0, stream>>>(fuset4, fuse);
    final_kernel<<<30720, 256, 0, stream>>>(x, labels, fuse, out);
}

// Round 5
// 425.401 us; speedup vs baseline: 1.0070x; 1.0070x over previous
//
#include <hip/hip_runtime.h>

typedef unsigned short u16;
typedef unsigned int u32;
typedef __bf16 bf16_t;
typedef bf16_t bf16x8 __attribute__((ext_vector_type(8)));
typedef float f32x16 __attribute__((ext_vector_type(16)));

#define DIM 2048
#define HW  192
#define CP  256
#define NB  80

__device__ __forceinline__ u16 f2b(float f) {
    u32 u = __float_as_uint(f);
    u32 r = (u + 0x7FFFu + ((u >> 16) & 1u)) >> 16;   // RNE
    return (u16)r;
}

__device__ __forceinline__ void g2l16(const void* g, void* l) {
    __builtin_amdgcn_global_load_lds(
        (const __attribute__((address_space(1))) u32*)g,
        (__attribute__((address_space(3))) u32*)l, 16, 0, 0);
}

// T1 XCD swizzle: cluster consecutive (act-panel-sharing) block ids on one XCD.
// n must be divisible by 8; bijective chunked remap [m204].
__device__ __forceinline__ int xcdswz(int lid, int n) {
    return (lid & 7) * (n >> 3) + (lid >> 3);
}

// ---------------------------------------------------------------------------
// MFMA GEMM core v4. Block = 256 threads (4 waves). Output tile 192(n)x128(m);
// wave grid 2x2: wave w -> rows (w>>1)*96, cols (w&1)*64. Per wave: 3x2 MFMA
// tiles of 32x32 (mfma_f32_32x32x16_bf16), acc = 96 VGPRs/lane.
// Double-buffered LDS 41 KB: stage k+1 overlaps MFMA k.
// act: [192][K] bf16 k-major (row ptr via functor, stride arstride).
// W: [128][K] bf16 row stride wstride. XOR-chunk swizzle (chunk ^= (row>>1)&3)
// breaks bank aliasing of the 64B rows forced by global_load_lds.
// A/B frag: row = lane&31, k = (lane>>5)*8 + e. D: col = lane&31,
// row = (r&3) + 8*(r>>2) + 4*(lane>>5)  [m74/m101].
// ---------------------------------------------------------------------------
template<int ACT, bool OUTF32, typename F>   // ACT 0=none 1=relu
__device__ __forceinline__ void gemm_core(F actAddr, int arstride,
    const u16* __restrict__ Wp, int wstride, int K,
    void* __restrict__ outp, int M)
{
    __shared__ u16 act_s[2][192 * 32];
    __shared__ u16 w_s[2][128 * 32];
    const int t    = threadIdx.x;      // 0..255
    const int wv   = t >> 6;           // wave id
    const int wn   = wv >> 1;          // n-half: rows wn*96
    const int wm   = wv & 1;           // m-half: cols wm*64
    const int lane = t & 63;
    const int ln   = lane & 31;
    const int q2   = lane >> 5;        // 0/1
    const int swz  = (ln >> 1) & 3;

    f32x16 acc[3][2];
    #pragma unroll
    for (int i = 0; i < 3; ++i)
        #pragma unroll
        for (int j = 0; j < 2; ++j)
            #pragma unroll
            for (int r = 0; r < 16; ++r) acc[i][j][r] = 0.f;

    auto stage = [&](int buf, int k0) {
        const u16* ap = actAddr(k0);
        #pragma unroll
        for (int r = 0; r < 2; ++r) {            // W: 512 16B slots / 256 thr
            int idx = r * 256 + t;
            int row = idx >> 2, pc = idx & 3;
            int lc  = pc ^ ((row >> 1) & 3);
            g2l16(Wp + (size_t)row * wstride + k0 + lc * 8, (void*)(w_s[buf] + idx * 8));
        }
        #pragma unroll
        for (int r = 0; r < 3; ++r) {            // act: 768 16B slots / 256 thr
            int idx = r * 256 + t;
            int row = idx >> 2, pc = idx & 3;
            int lc  = pc ^ ((row >> 1) & 3);
            g2l16(ap + (size_t)row * arstride + lc * 8, (void*)(act_s[buf] + idx * 8));
        }
    };

    auto compute = [&](int buf) {
        #pragma unroll
        for (int s = 0; s < 2; ++s) {            // two 16-k steps per 32-k tile
            bf16x8 af[3], bf[2];
            const int phys = (s * 2 + q2) ^ swz;
            #pragma unroll
            for (int i = 0; i < 3; ++i)
                af[i] = *(const bf16x8*)(act_s[buf] + ((wn * 96 + i * 32 + ln) * 32 + phys * 8));
            #pragma unroll
            for (int j = 0; j < 2; ++j)
                bf[j] = *(const bf16x8*)(w_s[buf] + ((wm * 64 + j * 32 + ln) * 32 + phys * 8));
            #pragma unroll
            for (int i = 0; i < 3; ++i)
                #pragma unroll
                for (int j = 0; j < 2; ++j)
                    acc[i][j] = __builtin_amdgcn_mfma_f32_32x32x16_bf16(
                        af[i], bf[j], acc[i][j], 0, 0, 0);
        }
    };

    stage(0, 0);
    const int iters = K / 32;
    for (int it = 0; it < iters; ++it) {
        int b = it & 1;
        __syncthreads();                // waits prev stage's g2l + frag reads
        if (it + 1 < iters) stage(b ^ 1, (it + 1) * 32);
        compute(b);
    }

    #pragma unroll
    for (int i = 0; i < 3; ++i) {
        #pragma unroll
        for (int j = 0; j < 2; ++j) {
            #pragma unroll
            for (int r = 0; r < 16; ++r) {
                float v = acc[i][j][r];
                if (ACT == 1) v = v > 0.f ? v : 0.f;
                int nl = wn * 96 + i * 32 + (r & 3) + 8 * (r >> 2) + 4 * q2;
                int ml = wm * 64 + j * 32 + ln;
                if (OUTF32) ((float*)outp)[(size_t)nl * M + ml] = v;
                else        ((u16*)outp)[(size_t)nl * M + ml] = f2b(v);
            }
        }
    }
}

// proj, K-split x4: proj4[p][n][pix][o] = sum_{c in p*512..+512} x[n][c][pix]*Wr[o][c]
// fp32 partials. 640 blocks x 4 waves = 2.5 blocks/CU. XCD-swizzled.
// act source: channel-blocked xt2[z][cb][pix][cw] (cb=c>>6, cw=c&63) —
// row stride 64; 32-wide k-tiles never cross a 64-block.
__global__ __launch_bounds__(256) void proj_g(const u16* __restrict__ xt,
    const int* __restrict__ sub, int nbase,
    const u16* __restrict__ Wri, const u16* __restrict__ Wrv,
    float* __restrict__ proj4)
{
    const int nblk = gridDim.x * gridDim.z;
    const int lid  = blockIdx.x + gridDim.x * blockIdx.z;
    const int s    = xcdswz(lid, nblk);
    const int bm = s & 1, zz = s >> 1;
    const int z = zz >> 2, p = zz & 3;
    const int n = nbase + z;
    const u16* actz = xt + (size_t)z * (HW * DIM);
    const u16* Wp  = ((sub[n] != 0) ? Wri : Wrv) + (size_t)bm * 128 * DIM + p * 512;
    float* outp = proj4 + (size_t)p * ((size_t)NB * HW * CP)
                + (size_t)n * (HW * CP) + bm * 128;
    auto f = [=](int k0) {
        int gc = p * 512 + k0;
        return actz + (size_t)(gc >> 6) * (HW * 64) + (gc & 63);
    };
    gemm_core<0, true>(f, 64, Wp, DIM, 512, outp, CP);
}

// sum 4 K-slice partials -> bf16 projt
__global__ __launch_bounds__(256) void proj_red(const float* __restrict__ proj4,
                                                u16* __restrict__ projt)
{
    const size_t i = ((size_t)blockIdx.x * 256 + threadIdx.x) * 4;
    const size_t S = (size_t)NB * HW * CP;
    float4 a = *(const float4*)(proj4 + i);
    float4 b = *(const float4*)(proj4 + i + S);
    float4 c = *(const float4*)(proj4 + i + 2 * S);
    float4 d = *(const float4*)(proj4 + i + 3 * S);
    ushort4 o;
    o.x = f2b(a.x + b.x + c.x + d.x);
    o.y = f2b(a.y + b.y + c.y + d.y);
    o.z = f2b(a.z + b.z + c.z + d.z);
    o.w = f2b(a.w + b.w + c.w + d.w);
    *(ushort4*)(projt + i) = o;
}

// compose: st[id][br][p][o] = relu( sum_kk projt[samp][p][o2] * Wc[o][kk] )
// 256 blocks, XCD-swizzled (16 consecutive lids share one act panel).
__global__ __launch_bounds__(256) void compose_g(const u16* __restrict__ projt,
    const u16* __restrict__ Wci, const u16* __restrict__ Wcv,
    u16* __restrict__ st)
{
    const int lid = blockIdx.x + 16 * blockIdx.z;      // 0..255
    const int s   = xcdswz(lid, 256);
    const int bm = s & 15, z = s >> 4;
    const int br = z >> 3, id = z & 7;
    const u16* base = projt + (size_t)(id * 10 + br * 5) * (HW * CP);
    const u16* Wp   = (br ? Wcv : Wci) + (size_t)bm * 128 * 1280;
    u16* outp = st + (size_t)(id * 2 + br) * (HW * DIM) + bm * 128;
    auto f = [=](int k0) { return base + (size_t)(k0 >> 8) * (HW * CP) + (k0 & 255); };
    gemm_core<1, false>(f, CP, Wp, 1280, 1280, outp, DIM);
}

// fuse, K-split x4 (h=0..3 covers k = h*1024 of [s_i;s_v]); fp32 partials.
// 512 blocks, XCD-swizzled (16 consecutive lids share one act panel).
__global__ __launch_bounds__(256) void fuse_g(const u16* __restrict__ st,
    const u16* __restrict__ Wf, float* __restrict__ fuset4)
{
    const int lid = blockIdx.x + 16 * blockIdx.z;      // 0..511
    const int s   = xcdswz(lid, 512);
    const int bm = s & 15, z = s >> 4;
    const int h = z >> 3, id = z & 7;
    const u16* base = st + (size_t)(id * 2 + (h >> 1)) * (HW * DIM) + (h & 1) * 1024;
    const u16* Wp   = Wf + (size_t)bm * 128 * (2 * DIM) + (size_t)h * 1024;
    float* outp = fuset4 + (size_t)h * (8 * HW * DIM) + (size_t)id * (HW * DIM) + bm * 128;
    auto f = [=](int k0) { return base + k0; };
    gemm_core<0, true>(f, DIM, Wp, 2 * DIM, 1024, outp, DIM);
}

// prep: x transpose-convert + (optionally) weight fp32->bf16, one launch.
// b < nxt: tile [c=64][p=192(all)] of sample z: ONE contiguous 48KB read
// (12 float4/thread), bf16-convert BEFORE LDS (u16 ts[64][210]).
// Output layout is channel-blocked xt2[z][cb][p][64]: the block's whole
// 192x64 tile is ONE contiguous 24KB write (was 192 lines at 4KB stride —
// the 2.1TB/s limiter per R3/R4 profiles).
// b >= nxt: wcvt unit.
__global__ __launch_bounds__(256) void prep_k(const float* __restrict__ x,
    u16* __restrict__ xt, int nxt, int wc,
    const float* __restrict__ a0, const float* __restrict__ a1,
    const float* __restrict__ a2, const float* __restrict__ a3,
    const float* __restrict__ a4,
    u16* __restrict__ o0, u16* __restrict__ o1, u16* __restrict__ o2,
    u16* __restrict__ o3, u16* __restrict__ o4)
{
    __shared__ u16 ts[64][210];   // pad 210: 8-row groups spread 4 bank classes
    const int b = blockIdx.x;
    const int t = threadIdx.x;
    if (b < nxt) {
        const int z = b >> 5, cb = b & 31, c0 = cb * 64;
        const float* src = x + ((size_t)z * DIM + c0) * HW;   // 48KB contiguous
        #pragma unroll
        for (int i = 0; i < 12; ++i) {
            int idx = i * 256 + t;               // 0..3071 float4 slots
            float4 v = *(const float4*)(src + (size_t)idx * 4);
            int c = idx / 48, p4 = (idx % 48) * 4;
            u32 lo = ((u32)f2b(v.y) << 16) | f2b(v.x);
            u32 hi = ((u32)f2b(v.w) << 16) | f2b(v.z);
            *(u32*)&ts[c][p4]     = lo;
            *(u32*)&ts[c][p4 + 2] = hi;
        }
        __syncthreads();
        u16* dst = xt + ((size_t)z * 32 + cb) * (HW * 64);    // 24KB contiguous
        #pragma unroll
        for (int i = 0; i < 6; ++i) {
            int u = i * 256 + t;                 // 0..1535 units of (p, 8 c)
            int c8 = (u & 7) * 8, p = u >> 3;
            u32 w0 = ((u32)ts[c8 + 1][p] << 16) | ts[c8 + 0][p];
            u32 w1 = ((u32)ts[c8 + 3][p] << 16) | ts[c8 + 2][p];
            u32 w2 = ((u32)ts[c8 + 5][p] << 16) | ts[c8 + 4][p];
            u32 w3 = ((u32)ts[c8 + 7][p] << 16) | ts[c8 + 6][p];
            uint4 o4v; o4v.x = w0; o4v.y = w1; o4v.z = w2; o4v.w = w3;
            *(uint4*)(dst + (size_t)p * 64 + c8) = o4v;
        }
    } else if (wc) {
        size_t off = ((size_t)(b - nxt) * 256 + t) * 4;
        const float* s; u16* d;
        if (off < 524288)                    { s = a0; d = o0; }
        else if ((off -= 524288) < 524288)   { s = a1; d = o1; }
        else if ((off -= 524288) < 2621440)  { s = a2; d = o2; }
        else if ((off -= 2621440) < 2621440) { s = a3; d = o3; }
        else                                 { off -= 2621440; s = a4; d = o4; }
        float4 v = *(const float4*)(s + off);
        ushort4 p;
        p.x = f2b(v.x); p.y = f2b(v.y); p.z = f2b(v.z); p.w = f2b(v.w);
        *(ushort4*)(d + off) = p;
    }
}

// sum 4 K-split partials, sigmoid, transpose: fuse[id][c][p]
__global__ __launch_bounds__(256) void fuse_tr(const float* __restrict__ fuset4,
                                               float* __restrict__ fuse)
{
    __shared__ float ts[64][65];
    const int id = blockIdx.z;
    const int c0 = blockIdx.x * 64, p0 = blockIdx.y * 64;
    const int t = threadIdx.x, l = t & 63;
    const size_t hs = (size_t)8 * HW * DIM;
    #pragma unroll
    for (int i = 0; i < 16; ++i) {
        int pl = (t >> 6) * 16 + i;
        size_t a = ((size_t)id * HW + p0 + pl) * DIM + c0 + l;
        float v = fuset4[a] + fuset4[a + hs] + fuset4[a + 2 * hs] + fuset4[a + 3 * hs];
        ts[pl][l] = 1.f / (1.f + __expf(-v));
    }
    __syncthreads();
    #pragma unroll
    for (int i = 0; i < 16; ++i) {
        int cl = (t >> 6) * 16 + i;
        fuse[((size_t)id * DIM + c0 + cl) * HW + p0 + l] = ts[l][cl];
    }
}

// out[n][c][p] = x * (1 + fuse[labels[n]][c][p])
__global__ __launch_bounds__(256) void final_kernel(const float* __restrict__ x,
    const int* __restrict__ labels, const float* __restrict__ fusebuf,
    float* __restrict__ out)
{
    const u32 e = ((u32)blockIdx.x * 256u + threadIdx.x) * 4u;
    const u32 n   = e / ((u32)DIM * HW);
    const u32 rem = e % ((u32)DIM * HW);
    const int id  = labels[n];
    float4 xv = *reinterpret_cast<const float4*>(x + e);
    float4 fv = *reinterpret_cast<const float4*>(fusebuf + (size_t)id * DIM * HW + rem);
    float4 o;
    o.x = xv.x + xv.x * fv.x;
    o.y = xv.y + xv.y * fv.y;
    o.z = xv.z + xv.z * fv.z;
    o.w = xv.w + xv.w * fv.w;
    *reinterpret_cast<float4*>(out + e) = o;
}

extern "C" void kernel_launch(void* const* d_in, const int* in_sizes, int n_in,
                              void* d_out, int out_size, void* d_ws, size_t ws_size,
                              hipStream_t stream) {
    const float* x      = (const float*)d_in[0];
    const int*   labels = (const int*)d_in[1];
    const int*   sub    = (const int*)d_in[2];
    const float* Wri    = (const float*)d_in[3];
    const float* Wrv    = (const float*)d_in[4];
    const float* Wci    = (const float*)d_in[5];
    const float* Wcv    = (const float*)d_in[6];
    const float* Wf     = (const float*)d_in[7];
    float* out = (float*)d_out;
    char* ws = (char*)d_ws;

    const bool full = ws_size >= (size_t)175636480;
    const size_t xtb = full ? (size_t)62914560 : (size_t)15728640;

    u16* Wri_b = (u16*)(ws);
    u16* Wrv_b = (u16*)(ws + 1048576);
    u16* Wci_b = (u16*)(ws + 2097152);
    u16* Wcv_b = (u16*)(ws + 7340032);
    u16* Wf_b  = (u16*)(ws + 12582912);
    u16* xtbuf = (u16*)(ws + 29360128);
    u16* projt = (u16*)(ws + 29360128 + xtb);
    u16* stb   = (u16*)(ws + 29360128 + xtb + 7864320);
    float* fuset4 = (float*)(ws + 29360128 + xtb + 7864320 + 12582912);
    float* fuse   = (float*)(ws + 29360128 + xtb + 7864320 + 12582912 + 50331648);
    // proj4 (4 x 15.7 MB fp32 partials) reuses the fuset4+fuse region —
    // dead until fuse_g/fuse_tr; proj4 dead after proj_red.
    float* proj4 = fuset4;

    const int nchunk = full ? 1 : 4;
    const int cs = NB / nchunk;
    for (int c = 0; c < nchunk; ++c) {
        const int nxt = 32 * cs;
        const int wc = (c == 0) ? 1 : 0;
        prep_k<<<nxt + (wc ? 14336 : 0), 256, 0, stream>>>(
            x + (size_t)c * cs * DIM * HW, xtbuf, nxt, wc,
            Wri, Wrv, Wci, Wcv, Wf, Wri_b, Wrv_b, Wci_b, Wcv_b, Wf_b);
        proj_g<<<dim3(2, 1, cs * 4), 256, 0, stream>>>(xtbuf, sub, c * cs, Wri_b, Wrv_b, proj4);
    }
    proj_red<<<3840, 256, 0, stream>>>(proj4, projt);
    compose_g<<<dim3(16, 1, 16), 256, 0, stream>>>(projt, Wci_b, Wcv_b, stb);
    fuse_g   <<<dim3(16, 1, 32), 256, 0, stream>>>(stb, Wf_b, fuset4);
    fuse_tr  <<<dim3(32, 3, 8), 256, 0, stream>>>(fuset4, fuse);
    final_kernel<<<30720, 256, 0, stream>>>(x, labels, fuse, out);
}